// Round 1
// baseline (9081.468 us; speedup 1.0000x reference)
//
#include <hip/hip_runtime.h>
#include <math.h>

// Problem constants (from reference)
#define BB    64
#define FC    24
#define NN    1000
#define HID   64
#define EMBD  32
#define TT    48     // HIST + FC
#define FF    8
#define INSZ  33     // OUT + EMB

// Kernel tiling
#define CPB     64               // cells per block
#define SPLIT   4                // waves per block, each owns HID/SPLIT outputs
#define JPT     (HID / SPLIT)    // 16 j's per thread
#define TPB     (CPB * SPLIT)    // 256 threads
#define LSTRIDE 65               // padded LDS stride (bank-conflict free)

__device__ __forceinline__ float fast_sigmoid(float v) {
    // 1 / (1 + 2^(-v*log2(e)))
    float e = __builtin_amdgcn_exp2f(-1.4426950408889634f * v);
    return __builtin_amdgcn_rcpf(1.0f + e);
}

__device__ __forceinline__ float fast_tanh(float v) {
    // tanh(v) = 1 - 2/(2^(v*2*log2(e)) + 1), clamped for safety
    float vv = fminf(fmaxf(v, -15.0f), 15.0f);
    float e = __builtin_amdgcn_exp2f(2.8853900817779268f * vv);
    return 1.0f - 2.0f * __builtin_amdgcn_rcpf(e + 1.0f);
}

__global__ __launch_bounds__(TPB, 4) void gru_decoder(
    const float* __restrict__ X,    // [B][TT][N][F]
    const float* __restrict__ hn0,  // [B*N][HID]
    const float* __restrict__ xn,   // [B][N][1]
    const float* __restrict__ emb,  // [NEMB][EMBD]
    const float* __restrict__ Wih,  // [3*HID][INSZ]
    const float* __restrict__ Whh,  // [3*HID][HID]
    const float* __restrict__ bih,  // [3*HID]
    const float* __restrict__ bhh,  // [3*HID]
    const float* __restrict__ Wout, // [1][HID]
    const float* __restrict__ bout, // [1]
    float* __restrict__ out)        // [B][FC][N][1]
{
    __shared__ float hbuf[HID * LSTRIDE];

    const int tid = threadIdx.x;
    const int cl  = tid & (CPB - 1);   // cell-local 0..63
    const int g   = tid >> 6;          // j-group, uniform per wave
    const int cell = blockIdx.x * CPB + cl;
    const int b = cell / NN;
    const int n = cell - b * NN;

    // ---- stage h0 into LDS, coalesced ----
    const float* hsrc = hn0 + (size_t)blockIdx.x * CPB * HID;
    #pragma unroll
    for (int i = 0; i < (CPB * HID) / TPB; ++i) {
        int e   = i * TPB + tid;
        int row = e >> 6;     // cell-local
        int k   = e & 63;     // hidden index
        hbuf[k * LSTRIDE + row] = hsrc[e];
    }
    __syncthreads();

    // ---- h_old into registers ----
    float h[HID];
    #pragma unroll
    for (int k = 0; k < HID; ++k) h[k] = hbuf[k * LSTRIDE + cl];
    __syncthreads();   // nobody may write hbuf until everyone has read

    float x_prev = xn[cell];
    const int j0 = g * JPT;

    for (int t = 0; t < FC; ++t) {
        // ---- gather embedding for this step ----
        int idx = (int)X[(((size_t)b * TT + t) * NN + n) * FF + 7];
        float x[EMBD];
        const float4* e4 = (const float4*)(emb + idx * EMBD);
        #pragma unroll
        for (int q = 0; q < EMBD / 4; ++q) {
            float4 v = e4[q];
            x[4*q+0] = v.x; x[4*q+1] = v.y; x[4*q+2] = v.z; x[4*q+3] = v.w;
        }

        // ---- compute this thread's 16 outputs ----
        #pragma unroll 1
        for (int jj = 0; jj < JPT; ++jj) {
            int j = j0 + jj;   // wave-uniform
            const float* wr = Wih + (size_t)j * INSZ;
            const float* wz = Wih + (size_t)(64 + j) * INSZ;
            const float* wn = Wih + (size_t)(128 + j) * INSZ;
            float ar = bih[j]       + wr[0] * x_prev;
            float az = bih[64 + j]  + wz[0] * x_prev;
            float an = bih[128 + j] + wn[0] * x_prev;
            #pragma unroll
            for (int k = 0; k < EMBD; ++k) {
                float xv = x[k];
                ar = fmaf(wr[1 + k], xv, ar);
                az = fmaf(wz[1 + k], xv, az);
                an = fmaf(wn[1 + k], xv, an);
            }
            const float* vr = Whh + (size_t)j * HID;
            const float* vz = Whh + (size_t)(64 + j) * HID;
            const float* vn = Whh + (size_t)(128 + j) * HID;
            float hr = bhh[j];
            float hz = bhh[64 + j];
            float hv = bhh[128 + j];
            #pragma unroll
            for (int k = 0; k < HID; ++k) {
                float hk = h[k];
                hr = fmaf(vr[k], hk, hr);
                hz = fmaf(vz[k], hk, hz);
                hv = fmaf(vn[k], hk, hv);
            }
            float r  = fast_sigmoid(ar + hr);
            float z  = fast_sigmoid(az + hz);
            float nv = fast_tanh(an + r * hv);
            float hold = hbuf[j * LSTRIDE + cl];       // own slot: no cross-thread hazard
            float hnew = nv + z * (hold - nv);         // (1-z)*n + z*h
            hbuf[j * LSTRIDE + cl] = hnew;
        }
        __syncthreads();   // all h_new written

        // ---- read h_new, compute out-dot (every wave, avoids reduction) ----
        float o = bout[0];
        #pragma unroll
        for (int k = 0; k < HID; ++k) {
            float hk = hbuf[k * LSTRIDE + cl];
            h[k] = hk;
            o = fmaf(Wout[k], hk, o);
        }
        if (g == 0) out[((size_t)b * FC + t) * NN + n] = o;
        x_prev = o;
        __syncthreads();   // all reads done before next step's writes
    }
}

extern "C" void kernel_launch(void* const* d_in, const int* in_sizes, int n_in,
                              void* d_out, int out_size, void* d_ws, size_t ws_size,
                              hipStream_t stream) {
    (void)in_sizes; (void)n_in; (void)d_ws; (void)ws_size; (void)out_size;
    const float* X    = (const float*)d_in[0];
    const float* hn   = (const float*)d_in[1];
    const float* xn   = (const float*)d_in[2];
    const float* emb  = (const float*)d_in[3];
    const float* Wih  = (const float*)d_in[4];
    const float* Whh  = (const float*)d_in[5];
    const float* bih  = (const float*)d_in[6];
    const float* bhh  = (const float*)d_in[7];
    const float* Wout = (const float*)d_in[8];
    const float* bout = (const float*)d_in[9];
    float* out = (float*)d_out;

    const int cells = BB * NN;               // 64000
    const int blocks = cells / CPB;          // 1000
    gru_decoder<<<blocks, TPB, 0, stream>>>(X, hn, xn, emb, Wih, Whh,
                                            bih, bhh, Wout, bout, out);
}

// Round 2
// 1223.841 us; speedup vs baseline: 7.4205x; 7.4205x over previous
//
#include <hip/hip_runtime.h>
#include <math.h>

// Problem constants (from reference)
#define BB    64
#define FC    24
#define NN    1000
#define HID   64
#define EMBD  32
#define TT    48     // HIST + FC
#define FF    8
#define NEMB  1000
#define G3    (3 * HID)   // 192 gate rows
#define INSZ  33          // OUT + EMB

// Kernel tiling
#define CPB     64               // cells per block
#define SPLIT   4                // waves per block, each owns HID/SPLIT outputs
#define JPT     (HID / SPLIT)    // 16 j's per thread
#define TPB     (CPB * SPLIT)    // 256 threads
#define LSTRIDE 65               // padded LDS stride (bank-conflict free)

__device__ __forceinline__ float fast_sigmoid(float v) {
    float e = __builtin_amdgcn_exp2f(-1.4426950408889634f * v);
    return __builtin_amdgcn_rcpf(1.0f + e);
}

__device__ __forceinline__ float fast_tanh(float v) {
    float vv = fminf(fmaxf(v, -15.0f), 15.0f);
    float e = __builtin_amdgcn_exp2f(2.8853900817779268f * vv);
    return 1.0f - 2.0f * __builtin_amdgcn_rcpf(e + 1.0f);
}

// P[e][gj] = bih[gj] + (gj<128 ? bhh[gj] : 0) + sum_k emb[e][k]*Wih[gj][1+k]
// (bhh of the n-gate must stay inside the r-multiplied term, so not folded)
__global__ __launch_bounds__(G3) void premul_kernel(
    const float* __restrict__ emb, const float* __restrict__ Wih,
    const float* __restrict__ bih, const float* __restrict__ bhh,
    float* __restrict__ P)
{
    __shared__ float xe[EMBD];
    const int e = blockIdx.x;
    const int j = threadIdx.x;          // 0..191
    if (j < EMBD) xe[j] = emb[e * EMBD + j];
    __syncthreads();
    float acc = bih[j] + (j < 2 * HID ? bhh[j] : 0.0f);
    const float* w = Wih + (size_t)j * INSZ + 1;
    #pragma unroll
    for (int k = 0; k < EMBD; ++k) acc = fmaf(w[k], xe[k], acc);
    P[e * G3 + j] = acc;
}

__global__ __launch_bounds__(TPB) __attribute__((amdgpu_waves_per_eu(4, 4)))
void gru_decoder(
    const float* __restrict__ X,    // [B][TT][N][F]
    const float* __restrict__ hn0,  // [B*N][HID]
    const float* __restrict__ xn,   // [B][N][1]
    const float* __restrict__ Whh,  // [3*HID][HID]
    const float* __restrict__ bhh,  // [3*HID]
    const float* __restrict__ Wih,  // [3*HID][INSZ]
    const float* __restrict__ Wout, // [1][HID]
    const float* __restrict__ bout, // [1]
    const float* __restrict__ P,    // [NEMB][192] precomputed
    float* __restrict__ out)        // [B][FC][N][1]
{
    __shared__ float hbuf[HID * LSTRIDE];

    const int tid = threadIdx.x;
    const int cl  = tid & (CPB - 1);   // cell-local 0..63
    const int g   = tid >> 6;          // j-group, uniform per wave
    const int cell = blockIdx.x * CPB + cl;
    const int b = cell / NN;
    const int n = cell - b * NN;

    // ---- stage h0 into LDS, coalesced ----
    const float* hsrc = hn0 + (size_t)blockIdx.x * CPB * HID;
    #pragma unroll
    for (int i = 0; i < (CPB * HID) / TPB; ++i) {
        int e = i * TPB + tid;
        hbuf[(e & 63) * LSTRIDE + (e >> 6)] = hsrc[e];
    }
    __syncthreads();

    // ---- h_old into registers ----
    float h[HID];
    #pragma unroll
    for (int k = 0; k < HID; ++k) h[k] = hbuf[k * LSTRIDE + cl];
    __syncthreads();   // nobody may write hbuf until everyone has read

    float x_prev = xn[cell];
    // Force wave-uniformity so weight loads become s_load (SGPR, no VGPR cost)
    const int j0 = __builtin_amdgcn_readfirstlane(g * JPT);

    for (int t = 0; t < FC; ++t) {
        const int idx = (int)X[(((size_t)b * TT + t) * NN + n) * FF + 7];
        const float* Prow = P + (size_t)idx * G3;

        #pragma unroll 1
        for (int jj = 0; jj < JPT; ++jj) {
            const int j = j0 + jj;   // wave-uniform
            // per-lane gathers of precomputed input-gate terms (L2-resident)
            float pr = Prow[j];
            float pz = Prow[HID + j];
            float pn = Prow[2 * HID + j];
            // wave-uniform weight rows -> scalar loads
            const float* vr = Whh + (size_t)j * HID;
            const float* vz = Whh + (size_t)(HID + j) * HID;
            const float* vn = Whh + (size_t)(2 * HID + j) * HID;
            float ar = fmaf(Wih[(size_t)j * INSZ],             x_prev, pr);
            float az = fmaf(Wih[(size_t)(HID + j) * INSZ],     x_prev, pz);
            float an = fmaf(Wih[(size_t)(2 * HID + j) * INSZ], x_prev, pn);
            float hr = 0.0f, hz = 0.0f;
            float hv = bhh[2 * HID + j];   // n-gate hidden bias (not foldable)
            #pragma unroll
            for (int k = 0; k < HID; ++k) {
                float hk = h[k];
                hr = fmaf(vr[k], hk, hr);
                hz = fmaf(vz[k], hk, hz);
                hv = fmaf(vn[k], hk, hv);
            }
            float r  = fast_sigmoid(ar + hr);
            float z  = fast_sigmoid(az + hz);
            float nv = fast_tanh(an + r * hv);
            float hold = hbuf[j * LSTRIDE + cl];   // own slot, no hazard
            float hnew = nv + z * (hold - nv);     // (1-z)*n + z*h
            hbuf[j * LSTRIDE + cl] = hnew;
        }
        __syncthreads();   // all h_new written

        // ---- read h_new, compute out-dot (all waves; avoids reduction) ----
        float o = bout[0];
        #pragma unroll
        for (int k = 0; k < HID; ++k) {
            float hk = hbuf[k * LSTRIDE + cl];
            h[k] = hk;
            o = fmaf(Wout[k], hk, o);   // Wout uniform -> SGPR
        }
        if (g == 0) out[((size_t)b * FC + t) * NN + n] = o;
        x_prev = o;
        __syncthreads();   // all reads done before next step's writes
    }
}

extern "C" void kernel_launch(void* const* d_in, const int* in_sizes, int n_in,
                              void* d_out, int out_size, void* d_ws, size_t ws_size,
                              hipStream_t stream) {
    (void)in_sizes; (void)n_in; (void)out_size; (void)ws_size;
    const float* X    = (const float*)d_in[0];
    const float* hn   = (const float*)d_in[1];
    const float* xn   = (const float*)d_in[2];
    const float* emb  = (const float*)d_in[3];
    const float* Wih  = (const float*)d_in[4];
    const float* Whh  = (const float*)d_in[5];
    const float* bih  = (const float*)d_in[6];
    const float* bhh  = (const float*)d_in[7];
    const float* Wout = (const float*)d_in[8];
    const float* bout = (const float*)d_in[9];
    float* out = (float*)d_out;
    float* P   = (float*)d_ws;            // 1000*192*4 = 768 KB scratch

    premul_kernel<<<NEMB, G3, 0, stream>>>(emb, Wih, bih, bhh, P);

    const int blocks = (BB * NN) / CPB;   // 1000
    gru_decoder<<<blocks, TPB, 0, stream>>>(X, hn, xn, Whh, bhh, Wih,
                                            Wout, bout, P, out);
}

// Round 3
// 293.481 us; speedup vs baseline: 30.9440x; 4.1701x over previous
//
#include <hip/hip_runtime.h>
#include <math.h>

// Problem constants
#define BB   64
#define FC   24
#define NN   1000
#define HID  64
#define EMBD 32
#define TT   48
#define FF   8
#define NEMB 1000
#define G3   192
#define INSZ 33

// Tiling
#define CPB  64     // cells per block (M)
#define TPB  256    // 4 waves
#define AST  72     // Abuf stride in bf16 elems (padded: 2-way max on MFMA reads)

typedef __attribute__((ext_vector_type(8))) short bf16x8;
typedef __attribute__((ext_vector_type(4))) float f32x4;

static __device__ __forceinline__ unsigned short f2bf(float f) {
    unsigned u = __builtin_bit_cast(unsigned, f);
    u += 0x7FFFu + ((u >> 16) & 1u);      // RNE
    return (unsigned short)(u >> 16);
}
static __device__ __forceinline__ float fast_sigmoid(float v) {
    float e = __builtin_amdgcn_exp2f(-1.4426950408889634f * v);
    return __builtin_amdgcn_rcpf(1.0f + e);
}
static __device__ __forceinline__ float fast_tanh(float v) {
    float vv = fminf(fmaxf(v, -15.0f), 15.0f);
    float e = __builtin_amdgcn_exp2f(2.8853900817779268f * vv);
    return 1.0f - 2.0f * __builtin_amdgcn_rcpf(e + 1.0f);
}

// P3[e][jc][gate] = bih[row] + (gate<2 ? bhh[row] : 0) + sum_k emb[e][k]*Wih[row][1+k]
// row = gate*64 + jc.  (n-gate bhh stays inside the r-multiplied term.)
__global__ __launch_bounds__(G3) void premul_kernel(
    const float* __restrict__ emb, const float* __restrict__ Wih,
    const float* __restrict__ bih, const float* __restrict__ bhh,
    float* __restrict__ P3)
{
    __shared__ float xe[EMBD];
    const int e = blockIdx.x;
    const int j = threadIdx.x;          // 0..191 (gate-row)
    if (j < EMBD) xe[j] = emb[e * EMBD + j];
    __syncthreads();
    float acc = bih[j] + (j < 2 * HID ? bhh[j] : 0.0f);
    const float* w = Wih + (size_t)j * INSZ + 1;
    #pragma unroll
    for (int k = 0; k < EMBD; ++k) acc = fmaf(w[k], xe[k], acc);
    P3[(size_t)e * G3 + (j & 63) * 3 + (j >> 6)] = acc;
}

__global__ __launch_bounds__(TPB) void gru_decoder(
    const float* __restrict__ X,    // [B][TT][N][F]
    const float* __restrict__ hn0,  // [B*N][HID]
    const float* __restrict__ xn,   // [B][N][1]
    const float* __restrict__ Whh,  // [3*HID][HID]
    const float* __restrict__ bhh,  // [3*HID]
    const float* __restrict__ Wih,  // [3*HID][INSZ]
    const float* __restrict__ Wout, // [1][HID]
    const float* __restrict__ bout, // [1]
    const float* __restrict__ P3,   // [NEMB][64][3]
    float* __restrict__ out)        // [B][FC][N][1]
{
    __shared__ __align__(16) unsigned short Abuf[CPB * AST]; // 9216 B, bf16 H
    __shared__ int   idxbuf[FC * CPB];                       // 6144 B
    __shared__ float xbuf[CPB];
    __shared__ float obuf[4 * CPB];
    __shared__ float Woutlds[HID];

    const int tid  = threadIdx.x;
    const int lane = tid & 63;
    const int g    = tid >> 6;         // wave id 0..3
    const int quad = lane >> 4;
    const int l15  = lane & 15;
    const int jcol = g * 16 + l15;     // this lane's gate column 0..63
    const int rowb = quad * 4;

    // ---- stage idx for all FC steps ----
    for (int e = tid; e < FC * CPB; e += TPB) {
        int t  = e >> 6;
        int cl = e & 63;
        int cell = blockIdx.x * CPB + cl;
        int b = cell / NN, n = cell - b * NN;
        idxbuf[e] = (int)X[(((size_t)b * TT + t) * NN + n) * FF + 7];
    }
    if (tid < CPB) {
        int cell = blockIdx.x * CPB + tid;
        xbuf[tid] = xn[cell];
        Woutlds[tid] = Wout[tid];
    }

    // ---- persistent B fragments: Whh^T slices, bf16 (24 VGPRs) ----
    // B[k][n]: lane holds n = gate*64 + jcol, k = ks*32 + quad*8 + elem
    bf16x8 Bf[3][2];
    #pragma unroll
    for (int gate = 0; gate < 3; ++gate) {
        #pragma unroll
        for (int ks = 0; ks < 2; ++ks) {
            const float* src = Whh + (size_t)(gate * HID + jcol) * HID + ks * 32 + quad * 8;
            float4 lo = *(const float4*)src;
            float4 hi = *(const float4*)(src + 4);
            bf16x8 f;
            f[0] = (short)f2bf(lo.x); f[1] = (short)f2bf(lo.y);
            f[2] = (short)f2bf(lo.z); f[3] = (short)f2bf(lo.w);
            f[4] = (short)f2bf(hi.x); f[5] = (short)f2bf(hi.y);
            f[6] = (short)f2bf(hi.z); f[7] = (short)f2bf(hi.w);
            Bf[gate][ks] = f;
        }
    }

    const float w0r = Wih[(size_t)jcol * INSZ];
    const float w0z = Wih[(size_t)(HID + jcol) * INSZ];
    const float w0n = Wih[(size_t)(2 * HID + jcol) * INSZ];
    const float bhn = bhh[2 * HID + jcol];
    const float bout0 = bout[0];

    // ---- h0: fp32 in regs (this lane's 16 (cell,jcol) pairs) + bf16 Abuf ----
    float hold[4][4];
    #pragma unroll
    for (int mt = 0; mt < 4; ++mt) {
        #pragma unroll
        for (int rr = 0; rr < 4; ++rr) {
            int m = mt * 16 + rowb + rr;
            float h = hn0[((size_t)blockIdx.x * CPB + m) * HID + jcol];
            hold[mt][rr] = h;
            Abuf[m * AST + jcol] = f2bf(h);
        }
    }
    __syncthreads();

    for (int t = 0; t < FC; ++t) {
        // ---- phase A: G = H · Whh^T on the matrix pipe ----
        f32x4 accr[4], accz[4], accn[4];
        #pragma unroll
        for (int mt = 0; mt < 4; ++mt) {
            const bf16x8 a0 = *(const bf16x8*)&Abuf[(mt * 16 + l15) * AST + quad * 8];
            const bf16x8 a1 = *(const bf16x8*)&Abuf[(mt * 16 + l15) * AST + 32 + quad * 8];
            f32x4 z4 = {0.f, 0.f, 0.f, 0.f};
            accr[mt] = __builtin_amdgcn_mfma_f32_16x16x32_bf16(a0, Bf[0][0], z4, 0, 0, 0);
            accr[mt] = __builtin_amdgcn_mfma_f32_16x16x32_bf16(a1, Bf[0][1], accr[mt], 0, 0, 0);
            accz[mt] = __builtin_amdgcn_mfma_f32_16x16x32_bf16(a0, Bf[1][0], z4, 0, 0, 0);
            accz[mt] = __builtin_amdgcn_mfma_f32_16x16x32_bf16(a1, Bf[1][1], accz[mt], 0, 0, 0);
            accn[mt] = __builtin_amdgcn_mfma_f32_16x16x32_bf16(a0, Bf[2][0], z4, 0, 0, 0);
            accn[mt] = __builtin_amdgcn_mfma_f32_16x16x32_bf16(a1, Bf[2][1], accn[mt], 0, 0, 0);
        }
        __syncthreads();   // Abuf reads done; xbuf/idx stable

        // ---- phase B: gates + h update, directly on accumulators ----
        #pragma unroll
        for (int mt = 0; mt < 4; ++mt) {
            #pragma unroll
            for (int rr = 0; rr < 4; ++rr) {
                int m   = mt * 16 + rowb + rr;
                int idx = idxbuf[t * CPB + m];
                float xp = xbuf[m];
                const float* pp = P3 + (size_t)idx * G3 + jcol * 3;
                float ar = fmaf(w0r, xp, pp[0]);
                float az = fmaf(w0z, xp, pp[1]);
                float an = fmaf(w0n, xp, pp[2]);
                float r  = fast_sigmoid(ar + accr[mt][rr]);
                float z  = fast_sigmoid(az + accz[mt][rr]);
                float nv = fast_tanh(an + r * (accn[mt][rr] + bhn));
                float hnew = nv + z * (hold[mt][rr] - nv);
                hold[mt][rr] = hnew;
                Abuf[m * AST + jcol] = f2bf(hnew);
            }
        }
        __syncthreads();   // h_new complete in Abuf

        // ---- phase C: out-dot partials from Abuf ----
        {
            const int c = tid & 63;
            const int q = tid >> 6;
            float o = 0.f;
            #pragma unroll
            for (int e2 = 0; e2 < 8; ++e2) {
                unsigned v = *(const unsigned*)&Abuf[c * AST + q * 16 + 2 * e2];
                float hlo = __builtin_bit_cast(float, v << 16);
                float hhi = __builtin_bit_cast(float, v & 0xFFFF0000u);
                o = fmaf(Woutlds[q * 16 + 2 * e2],     hlo, o);
                o = fmaf(Woutlds[q * 16 + 2 * e2 + 1], hhi, o);
            }
            obuf[q * CPB + c] = o;
        }
        __syncthreads();

        // ---- phase D: reduce, write out, feed back x_prev ----
        if (tid < CPB) {
            int cell = blockIdx.x * CPB + tid;
            int b = cell / NN, n = cell - b * NN;
            float o = bout0 + obuf[tid] + obuf[CPB + tid]
                    + obuf[2 * CPB + tid] + obuf[3 * CPB + tid];
            out[((size_t)b * FC + t) * NN + n] = o;
            xbuf[tid] = o;
        }
        __syncthreads();
    }
}

extern "C" void kernel_launch(void* const* d_in, const int* in_sizes, int n_in,
                              void* d_out, int out_size, void* d_ws, size_t ws_size,
                              hipStream_t stream) {
    (void)in_sizes; (void)n_in; (void)out_size; (void)ws_size;
    const float* X    = (const float*)d_in[0];
    const float* hn   = (const float*)d_in[1];
    const float* xn   = (const float*)d_in[2];
    const float* emb  = (const float*)d_in[3];
    const float* Wih  = (const float*)d_in[4];
    const float* Whh  = (const float*)d_in[5];
    const float* bih  = (const float*)d_in[6];
    const float* bhh  = (const float*)d_in[7];
    const float* Wout = (const float*)d_in[8];
    const float* bout = (const float*)d_in[9];
    float* out = (float*)d_out;
    float* P3  = (float*)d_ws;            // 1000*192*4 = 768 KB (fits, proven R1)

    premul_kernel<<<NEMB, G3, 0, stream>>>(emb, Wih, bih, bhh, P3);

    const int blocks = (BB * NN) / CPB;   // 1000
    gru_decoder<<<blocks, TPB, 0, stream>>>(X, hn, xn, Whh, bhh, Wih,
                                            Wout, bout, P3, out);
}

// Round 4
// 267.626 us; speedup vs baseline: 33.9334x; 1.0966x over previous
//
#include <hip/hip_runtime.h>
#include <math.h>

// Problem constants
#define BB   64
#define FC   24
#define NN   1000
#define HID  64
#define EMBD 32
#define TT   48
#define FF   8
#define NEMB 1000
#define G3   192
#define INSZ 33

// Decoder tiling
#define CPB  32     // cells per block (M)
#define TPB  256    // 4 waves
#define MT   2      // m-tiles of 16
#define AST  72     // Abuf stride in bf16 elems

// Premul tiling
#define EPB  8      // embeddings per block

typedef __attribute__((ext_vector_type(8))) short bf16x8;
typedef __attribute__((ext_vector_type(4))) float f32x4;

static __device__ __forceinline__ unsigned short f2bf(float f) {
    unsigned u = __builtin_bit_cast(unsigned, f);
    u += 0x7FFFu + ((u >> 16) & 1u);      // RNE
    return (unsigned short)(u >> 16);
}
static __device__ __forceinline__ float fast_sigmoid(float v) {
    float e = __builtin_amdgcn_exp2f(-1.4426950408889634f * v);
    return __builtin_amdgcn_rcpf(1.0f + e);
}
static __device__ __forceinline__ float fast_tanh(float v) {
    float vv = fminf(fmaxf(v, -15.0f), 15.0f);
    float e = __builtin_amdgcn_exp2f(2.8853900817779268f * vv);
    return 1.0f - 2.0f * __builtin_amdgcn_rcpf(e + 1.0f);
}

// P3[e][jc][gate] = bih[row] + (gate<2 ? bhh[row] : 0) + sum_k emb[e][k]*Wih[row][1+k]
// row = gate*64+jc. Coalesced: Wih staged transposed in LDS, 8 e per block.
__global__ __launch_bounds__(256) void premul_kernel(
    const float* __restrict__ emb, const float* __restrict__ Wih,
    const float* __restrict__ bih, const float* __restrict__ bhh,
    float* __restrict__ P3)
{
    __shared__ float Wihs[INSZ * G3];   // [k][j] transposed, 25 KB
    __shared__ float xes[EPB * EMBD];   // 1 KB
    const int tid = threadIdx.x;
    const int e0  = blockIdx.x * EPB;

    for (int i = tid; i < G3 * INSZ; i += 256) {     // coalesced global read
        int j = i / INSZ, k = i - j * INSZ;
        Wihs[k * G3 + j] = Wih[i];
    }
    xes[tid] = emb[(size_t)e0 * EMBD + tid];         // 256 == EPB*EMBD
    __syncthreads();

    const int el = tid >> 5;                          // 0..7
    const float* xe = xes + el * EMBD;
    #pragma unroll
    for (int i = 0; i < G3 / 32; ++i) {
        int j = (tid & 31) + 32 * i;                  // gate-row 0..191
        float acc = bih[j] + (j < 2 * HID ? bhh[j] : 0.0f);
        #pragma unroll
        for (int k = 0; k < EMBD; ++k)
            acc = fmaf(Wihs[(k + 1) * G3 + j], xe[k], acc);
        P3[(size_t)(e0 + el) * G3 + (j & 63) * 3 + (j >> 6)] = acc;
    }
}

__global__ __launch_bounds__(TPB) __attribute__((amdgpu_waves_per_eu(4)))
void gru_decoder(
    const float* __restrict__ X,    // [B][TT][N][F]
    const float* __restrict__ hn0,  // [B*N][HID]
    const float* __restrict__ xn,   // [B][N][1]
    const float* __restrict__ Whh,  // [3*HID][HID]
    const float* __restrict__ bhh,  // [3*HID]
    const float* __restrict__ Wih,  // [3*HID][INSZ]
    const float* __restrict__ Wout, // [1][HID]
    const float* __restrict__ bout, // [1]
    const float* __restrict__ P3,   // [NEMB][64][3]
    float* __restrict__ out)        // [B][FC][N][1]
{
    __shared__ __align__(16) unsigned short Abuf[CPB * AST]; // 4608 B bf16 H
    __shared__ int   idxbuf[FC * CPB];                       // 3072 B
    __shared__ float xbuf[CPB];

    const int tid  = threadIdx.x;
    const int lane = tid & 63;
    const int g    = tid >> 6;         // wave 0..3, owns gate-cols g*16..g*16+15
    const int quad = lane >> 4;
    const int l15  = lane & 15;
    const int jcol = g * 16 + l15;
    const int rowb = quad * 4;
    const int cell0 = blockIdx.x * CPB;

    // ---- stage idx for all FC steps (3 coalesced-ish rounds) ----
    for (int e = tid; e < FC * CPB; e += TPB) {
        int t = e >> 5, m = e & 31;
        int cell = cell0 + m;
        int b = cell / NN, n = cell - b * NN;
        idxbuf[t * CPB + m] = (int)X[(((size_t)b * TT + t) * NN + n) * FF + 7];
    }
    if (tid < CPB) xbuf[tid] = xn[cell0 + tid];

    // ---- persistent B fragments: Whh^T, bf16 (24 VGPRs) ----
    bf16x8 Bf[3][2];
    #pragma unroll
    for (int gate = 0; gate < 3; ++gate) {
        #pragma unroll
        for (int ks = 0; ks < 2; ++ks) {
            const float* src = Whh + (size_t)(gate * HID + jcol) * HID + ks * 32 + quad * 8;
            float4 lo = *(const float4*)src;
            float4 hi = *(const float4*)(src + 4);
            bf16x8 f;
            f[0] = (short)f2bf(lo.x); f[1] = (short)f2bf(lo.y);
            f[2] = (short)f2bf(lo.z); f[3] = (short)f2bf(lo.w);
            f[4] = (short)f2bf(hi.x); f[5] = (short)f2bf(hi.y);
            f[6] = (short)f2bf(hi.z); f[7] = (short)f2bf(hi.w);
            Bf[gate][ks] = f;
        }
    }

    const float w0r = Wih[(size_t)jcol * INSZ];
    const float w0z = Wih[(size_t)(HID + jcol) * INSZ];
    const float w0n = Wih[(size_t)(2 * HID + jcol) * INSZ];
    const float bhn = bhh[2 * HID + jcol];
    const float bout0 = bout[0];

    // ---- out-dot role: wave g covers cells g*8..g*8+7, 8 lanes/cell ----
    const int cd_m   = g * 8 + (lane & 7);
    const int kslice = lane >> 3;          // 0..7, 8 k's each
    float wout_r[8];
    #pragma unroll
    for (int e2 = 0; e2 < 8; ++e2) wout_r[e2] = Wout[kslice * 8 + e2];
    const int cd_cell = cell0 + cd_m;
    const int cd_b = cd_cell / NN, cd_n = cd_cell - cd_b * NN;
    const size_t obase = (size_t)cd_b * FC * NN + cd_n;

    // ---- h0: fp32 regs + bf16 Abuf ----
    float hold[MT][4];
    #pragma unroll
    for (int mt = 0; mt < MT; ++mt) {
        #pragma unroll
        for (int rr = 0; rr < 4; ++rr) {
            int m = mt * 16 + rowb + rr;
            float h = hn0[((size_t)cell0 + m) * HID + jcol];
            hold[mt][rr] = h;
            Abuf[m * AST + jcol] = f2bf(h);
        }
    }
    __syncthreads();

    for (int t = 0; t < FC; ++t) {
        // ---- phase A: G = H·Whh^T on matrix pipe (reads Abuf) ----
        f32x4 accr[MT], accz[MT], accn[MT];
        #pragma unroll
        for (int mt = 0; mt < MT; ++mt) {
            const bf16x8 a0 = *(const bf16x8*)&Abuf[(mt * 16 + l15) * AST + quad * 8];
            const bf16x8 a1 = *(const bf16x8*)&Abuf[(mt * 16 + l15) * AST + 32 + quad * 8];
            f32x4 z4 = {0.f, 0.f, 0.f, 0.f};
            accr[mt] = __builtin_amdgcn_mfma_f32_16x16x32_bf16(a0, Bf[0][0], z4, 0, 0, 0);
            accr[mt] = __builtin_amdgcn_mfma_f32_16x16x32_bf16(a1, Bf[0][1], accr[mt], 0, 0, 0);
            accz[mt] = __builtin_amdgcn_mfma_f32_16x16x32_bf16(a0, Bf[1][0], z4, 0, 0, 0);
            accz[mt] = __builtin_amdgcn_mfma_f32_16x16x32_bf16(a1, Bf[1][1], accz[mt], 0, 0, 0);
            accn[mt] = __builtin_amdgcn_mfma_f32_16x16x32_bf16(a0, Bf[2][0], z4, 0, 0, 0);
            accn[mt] = __builtin_amdgcn_mfma_f32_16x16x32_bf16(a1, Bf[2][1], accn[mt], 0, 0, 0);
        }

        // ---- overlapped: out-dot for step t-1 (also only reads Abuf) ----
        if (t > 0) {
            bf16x8 hv = *(const bf16x8*)&Abuf[cd_m * AST + kslice * 8];
            const unsigned* hv32 = (const unsigned*)&hv;
            float o = 0.f;
            #pragma unroll
            for (int q = 0; q < 4; ++q) {
                unsigned v = hv32[q];
                o = fmaf(wout_r[2 * q],     __builtin_bit_cast(float, v << 16),         o);
                o = fmaf(wout_r[2 * q + 1], __builtin_bit_cast(float, v & 0xFFFF0000u), o);
            }
            o += __shfl_xor(o, 8);
            o += __shfl_xor(o, 16);
            o += __shfl_xor(o, 32);
            if (lane < 8) {
                float oo = o + bout0;
                out[obase + (size_t)(t - 1) * NN] = oo;
                xbuf[cd_m] = oo;
            }
        }
        __syncthreads();   // xbuf ready; Abuf reads drained before B writes

        // ---- phase B: gates + h update ----
        #pragma unroll
        for (int mt = 0; mt < MT; ++mt) {
            #pragma unroll
            for (int rr = 0; rr < 4; ++rr) {
                int m   = mt * 16 + rowb + rr;
                int idx = idxbuf[t * CPB + m];
                float xp = xbuf[m];
                const float* pp = P3 + (size_t)idx * G3 + jcol * 3;
                float ar = fmaf(w0r, xp, pp[0]);
                float az = fmaf(w0z, xp, pp[1]);
                float an = fmaf(w0n, xp, pp[2]);
                float r  = fast_sigmoid(ar + accr[mt][rr]);
                float z  = fast_sigmoid(az + accz[mt][rr]);
                float nv = fast_tanh(an + r * (accn[mt][rr] + bhn));
                float hnew = nv + z * (hold[mt][rr] - nv);
                hold[mt][rr] = hnew;
                Abuf[m * AST + jcol] = f2bf(hnew);
            }
        }
        __syncthreads();   // h_new complete for next A / out-dot
    }

    // ---- epilogue: out for final step ----
    {
        bf16x8 hv = *(const bf16x8*)&Abuf[cd_m * AST + kslice * 8];
        const unsigned* hv32 = (const unsigned*)&hv;
        float o = 0.f;
        #pragma unroll
        for (int q = 0; q < 4; ++q) {
            unsigned v = hv32[q];
            o = fmaf(wout_r[2 * q],     __builtin_bit_cast(float, v << 16),         o);
            o = fmaf(wout_r[2 * q + 1], __builtin_bit_cast(float, v & 0xFFFF0000u), o);
        }
        o += __shfl_xor(o, 8);
        o += __shfl_xor(o, 16);
        o += __shfl_xor(o, 32);
        if (lane < 8) out[obase + (size_t)(FC - 1) * NN] = o + bout0;
    }
}

extern "C" void kernel_launch(void* const* d_in, const int* in_sizes, int n_in,
                              void* d_out, int out_size, void* d_ws, size_t ws_size,
                              hipStream_t stream) {
    (void)in_sizes; (void)n_in; (void)out_size; (void)ws_size;
    const float* X    = (const float*)d_in[0];
    const float* hn   = (const float*)d_in[1];
    const float* xn   = (const float*)d_in[2];
    const float* emb  = (const float*)d_in[3];
    const float* Wih  = (const float*)d_in[4];
    const float* Whh  = (const float*)d_in[5];
    const float* bih  = (const float*)d_in[6];
    const float* bhh  = (const float*)d_in[7];
    const float* Wout = (const float*)d_in[8];
    const float* bout = (const float*)d_in[9];
    float* out = (float*)d_out;
    float* P3  = (float*)d_ws;            // 1000*192*4 = 768 KB

    premul_kernel<<<NEMB / EPB, 256, 0, stream>>>(emb, Wih, bih, bhh, P3);

    const int blocks = (BB * NN) / CPB;   // 2000
    gru_decoder<<<blocks, TPB, 0, stream>>>(X, hn, xn, Whh, bhh, Wih,
                                            Wout, bout, P3, out);
}